// Round 5
// baseline (68.448 us; speedup 1.0000x reference)
//
#include <hip/hip_runtime.h>

#define HH 48
#define WW 48
#define HW 2304   // 48*48
#define NB 8      // N
#define CB 4      // COLOR
#define TB 3      // RGB

// pred_img_i[b,n,t,y,x] = 0.25 * sum_c sum_s kw[b,n,s,t,y,x] *
//     sum_{i,j in KxK} c1[b,n,cur_s+i,c,t,y,x]*c2[b,n,cur_s+j,c,t,y,x]
//                      * F[b,n,c, y+i+p_s-3, x+j+p_s-3]
// s=0:K=7,cur=9  s=1:K=5,cur=4  s=2:K=3,cur=1  s=3:K=1,cur=0

// ---- main: one thread per (b,n,c,t,pix); register-capped for occupancy ----
// __launch_bounds__(256, 6): 6 waves/EU min -> VGPR <= 85. Essential live set
// ~55 regs (32 core + 7 fp row + 4 acc + addr), so no spill expected.
__global__ __launch_bounds__(256, 6) void kconv_part(
    const float* __restrict__ frames,   // (4, 8, 4, 48, 48)
    const float* __restrict__ core,     // (4, 3072, 48, 48)  ch=((n*32+q)*4+c)*3+t
    const float* __restrict__ kw,       // (4, 8, 4, 3, 48, 48)
    float* __restrict__ part)           // (4, 8, 4, 3, 2304) partials
{
    const int tid = blockIdx.x * blockDim.x + threadIdx.x;  // 884736 total
    const int pix = tid % HW;
    int rem = tid / HW;
    const int t = rem % TB; rem /= TB;
    const int c = rem % CB; rem /= CB;
    const int n = rem % NB;
    const int b = rem / NB;
    const int x = pix % WW;
    const int y = pix / WW;

    // 32 core values for this (b,n,c,t,pix)
    const float* cp = core + ((size_t)b * 3072 + (size_t)((n * 32) * CB + c) * 3 + t) * HW + pix;
    float a[16], bv[16];
    #pragma unroll
    for (int q = 0; q < 16; ++q) {
        a[q]  = cp[(size_t)(q * 12) * HW];
        bv[q] = cp[(size_t)((q + 16) * 12) * HW];
    }

    const float* fb = frames + ((size_t)(b * NB + n) * CB + c) * HW;

    float r7 = 0.f, r5 = 0.f, r3 = 0.f, r1 = 0.f;
    #pragma unroll
    for (int i = 0; i < 7; ++i) {
        const int yy = y + i - 3;
        const bool yok = (yy >= 0) & (yy < HH);
        const int yyc = min(max(yy, 0), HH - 1);
        const float* frow = fb + yyc * WW;
        float fp[7];
        #pragma unroll
        for (int j = 0; j < 7; ++j) {
            const int xx = x + j - 3;
            const bool ok = yok & (xx >= 0) & (xx < WW);
            const int xxc = min(max(xx, 0), WW - 1);
            const float v = frow[xxc];          // branchless clamped load
            fp[j] = ok ? v : 0.f;
        }
        float in7 = 0.f;
        #pragma unroll
        for (int j = 0; j < 7; ++j) in7 = fmaf(bv[9 + j], fp[j], in7);
        r7 = fmaf(a[9 + i], in7, r7);
        if (i >= 1 && i <= 5) {
            float in5 = 0.f;
            #pragma unroll
            for (int j = 0; j < 5; ++j) in5 = fmaf(bv[4 + j], fp[1 + j], in5);
            r5 = fmaf(a[4 + i - 1], in5, r5);
        }
        if (i >= 2 && i <= 4) {
            float in3 = 0.f;
            #pragma unroll
            for (int j = 0; j < 3; ++j) in3 = fmaf(bv[1 + j], fp[2 + j], in3);
            r3 = fmaf(a[1 + i - 2], in3, r3);
        }
        if (i == 3) r1 = a[0] * bv[0] * fp[3];
    }

    // kw[b,n,s,t,pix] for s=0..3 (loaded late to keep early pressure low)
    const float* kwp = kw + ((size_t)(b * NB + n) * 12 + t) * HW + pix;
    const float kw0 = kwp[0];
    const float kw1 = kwp[(size_t)3 * HW];
    const float kw2 = kwp[(size_t)6 * HW];
    const float kw3 = kwp[(size_t)9 * HW];

    part[tid] = fmaf(kw0, r7, fmaf(kw1, r5, fmaf(kw2, r3, kw3 * r1)));
}

// pred_img_i[b,n,t,pix] = 0.25 * sum_c part[b,n,c,t,pix]
// pred_img[b,t,pix]     = mean_n pred_img_i[b,n,t,pix]
__global__ __launch_bounds__(256) void finish(
    const float* __restrict__ part, float* __restrict__ out, float* __restrict__ pm)
{
    const int tid = blockIdx.x * blockDim.x + threadIdx.x;  // 27648
    if (tid >= 4 * TB * HW) return;
    const int pix = tid % HW;
    const int t = (tid / HW) % TB;
    const int b = tid / (HW * TB);

    float m = 0.f;
    #pragma unroll
    for (int n = 0; n < NB; ++n) {
        const float* p = part + ((size_t)((b * NB + n) * CB) * TB + t) * HW + pix;
        float s = p[0] + p[(size_t)TB * HW] + p[(size_t)2 * TB * HW] + p[(size_t)3 * TB * HW];
        s *= 0.25f;
        out[((size_t)(b * NB + n) * TB + t) * HW + pix] = s;
        m += s;
    }
    pm[((size_t)b * TB + t) * HW + pix] = m * 0.125f;
}

// ---- fallback monolithic kernel (used only if ws too small) ----
__global__ __launch_bounds__(256) void kconv_kernel(
    const float* __restrict__ frames, const float* __restrict__ core,
    const float* __restrict__ kw, float* __restrict__ out)
{
    const int tid = blockIdx.x * blockDim.x + threadIdx.x;
    const int x = tid % WW;
    const int y = (tid / WW) % HH;
    const int n = (tid / HW) % NB;
    const int b = tid / (HW * NB);
    const int pix = y * WW + x;

    float kwv[4][3];
    {
        const float* kwp = kw + (size_t)((b * NB + n) * 12) * HW + pix;
        #pragma unroll
        for (int s = 0; s < 4; ++s)
            #pragma unroll
            for (int t = 0; t < TB; ++t)
                kwv[s][t] = kwp[(size_t)(s * 3 + t) * HW];
    }
    float acc[TB] = {0.f, 0.f, 0.f};
    const float* fbase = frames + (size_t)((b * NB + n) * CB) * HW;
    const float* cbase = core + (size_t)b * 3072 * HW + pix;
    for (int c = 0; c < CB; ++c) {
        float fpv[49];
        #pragma unroll
        for (int i = 0; i < 7; ++i) {
            const int yy = y + i - 3;
            #pragma unroll
            for (int j = 0; j < 7; ++j) {
                const int xx = x + j - 3;
                const bool ok = (yy >= 0) & (yy < HH) & (xx >= 0) & (xx < WW);
                fpv[i * 7 + j] = ok ? fbase[(size_t)c * HW + yy * WW + xx] : 0.f;
            }
        }
        #pragma unroll
        for (int t = 0; t < TB; ++t) {
            float a[16], bv[16];
            const float* cp = cbase + (size_t)(((n * 32) * CB + c) * 3 + t) * HW;
            #pragma unroll
            for (int q = 0; q < 16; ++q) {
                a[q]  = cp[(size_t)(q * 12) * HW];
                bv[q] = cp[(size_t)((q + 16) * 12) * HW];
            }
            float tot = 0.f;
            {
                float r = 0.f;
                #pragma unroll
                for (int i = 0; i < 7; ++i) {
                    float inner = 0.f;
                    #pragma unroll
                    for (int j = 0; j < 7; ++j) inner = fmaf(bv[9 + j], fpv[i * 7 + j], inner);
                    r = fmaf(a[9 + i], inner, r);
                }
                tot = fmaf(kwv[0][t], r, tot);
            }
            {
                float r = 0.f;
                #pragma unroll
                for (int i = 0; i < 5; ++i) {
                    float inner = 0.f;
                    #pragma unroll
                    for (int j = 0; j < 5; ++j) inner = fmaf(bv[4 + j], fpv[(1 + i) * 7 + 1 + j], inner);
                    r = fmaf(a[4 + i], inner, r);
                }
                tot = fmaf(kwv[1][t], r, tot);
            }
            {
                float r = 0.f;
                #pragma unroll
                for (int i = 0; i < 3; ++i) {
                    float inner = 0.f;
                    #pragma unroll
                    for (int j = 0; j < 3; ++j) inner = fmaf(bv[1 + j], fpv[(2 + i) * 7 + 2 + j], inner);
                    r = fmaf(a[1 + i], inner, r);
                }
                tot = fmaf(kwv[2][t], r, tot);
            }
            tot = fmaf(kwv[3][t], a[0] * bv[0] * fpv[3 * 7 + 3], tot);
            acc[t] += 0.25f * tot;
        }
    }
    float* op = out + (size_t)((b * NB + n) * TB) * HW + pix;
    op[0] = acc[0]; op[HW] = acc[1]; op[2 * HW] = acc[2];
}

__global__ __launch_bounds__(256) void mean_fb(
    const float* __restrict__ pii, float* __restrict__ pm)
{
    const int tid = blockIdx.x * blockDim.x + threadIdx.x;  // 27648
    if (tid >= 4 * TB * HW) return;
    const int pix3 = tid % (TB * HW);
    const int b = tid / (TB * HW);
    float s = 0.f;
    #pragma unroll
    for (int n = 0; n < NB; ++n)
        s += pii[(size_t)((b * NB + n) * TB) * HW + pix3];
    pm[tid] = s * 0.125f;
}

extern "C" void kernel_launch(void* const* d_in, const int* in_sizes, int n_in,
                              void* d_out, int out_size, void* d_ws, size_t ws_size,
                              hipStream_t stream) {
    const float* frames = (const float*)d_in[0];
    const float* core   = (const float*)d_in[1];
    const float* kw     = (const float*)d_in[2];
    float* out = (float*)d_out;                 // pred_img_i: 221184 floats
    float* pm  = out + 4 * NB * TB * HW;        // pred_img:   27648 floats

    const size_t part_elems = (size_t)4 * NB * CB * TB * HW;  // 884736
    if (ws_size >= part_elems * sizeof(float)) {
        float* part = (float*)d_ws;
        kconv_part<<<(int)(part_elems / 256), 256, 0, stream>>>(frames, core, kw, part);
        finish<<<(4 * TB * HW + 255) / 256, 256, 0, stream>>>(part, out, pm);
    } else {
        kconv_kernel<<<(4 * NB * HW) / 256, 256, 0, stream>>>(frames, core, kw, out);
        mean_fb<<<(4 * TB * HW + 255) / 256, 256, 0, stream>>>(out, pm);
    }
}

// Round 6
// 28.779 us; speedup vs baseline: 2.3784x; 2.3784x over previous
//
#include <hip/hip_runtime.h>

#define HH 48
#define WW 48
#define HW 2304   // 48*48
#define NB 8      // N
#define CB 4      // COLOR
#define TB 3      // RGB

// pred_img_i[b,n,t,y,x] = 0.25 * sum_c sum_s kw[b,n,s,t,y,x] *
//     sum_{i,j in KxK} c1[b,n,cur_s+i,c,t,y,x]*c2[b,n,cur_s+j,c,t,y,x]
//                      * F[b,n,c, y+i+p_s-3, x+j+p_s-3]
// s=0:K=7,cur=9  s=1:K=5,cur=4  s=2:K=3,cur=1  s=3:K=1,cur=0

// One thread per (b,n,c,t,pix). Phased structure to keep live VGPRs low:
//   phase 1: load bv[16] (column weights)
//   phase 2: row loop -> inner sums in7[7], in5[5], in3[3], f1 (fp[] transient)
//   phase 3: load a[16] + kw[4], final dot products, store partial
// NO launch_bounds occupancy cap (R5 lesson: cap => 40 VGPR + 117MB scratch spill).
__global__ __launch_bounds__(256) void kconv_part(
    const float* __restrict__ frames,   // (4, 8, 4, 48, 48)
    const float* __restrict__ core,     // (4, 3072, 48, 48)  ch=((n*32+q)*4+c)*3+t
    const float* __restrict__ kw,       // (4, 8, 4, 3, 48, 48)
    float* __restrict__ part)           // (4, 8, 4, 3, 2304) partials
{
    const int tid = blockIdx.x * blockDim.x + threadIdx.x;  // 884736 total
    const int pix = tid % HW;
    int rem = tid / HW;
    const int t = rem % TB; rem /= TB;
    const int c = rem % CB; rem /= CB;
    const int n = rem % NB;
    const int b = rem / NB;
    const int x = pix % WW;
    const int y = pix / WW;

    const float* cp = core + ((size_t)b * 3072 + (size_t)((n * 32) * CB + c) * 3 + t) * HW + pix;

    // phase 1: column weights bv[16]
    float bv[16];
    #pragma unroll
    for (int q = 0; q < 16; ++q)
        bv[q] = cp[(size_t)((q + 16) * 12) * HW];

    // x clamps/masks hoisted out of the row loop (7 instead of 49)
    int   xoff[7];
    float xmsk[7];
    #pragma unroll
    for (int j = 0; j < 7; ++j) {
        const int xx = x + j - 3;
        xoff[j] = min(max(xx, 0), WW - 1);
        xmsk[j] = ((xx >= 0) & (xx < WW)) ? 1.f : 0.f;
    }

    const float* fb = frames + ((size_t)(b * NB + n) * CB + c) * HW;

    // phase 2: per-row inner sums
    float in7[7], in5[5], in3[3], f1 = 0.f;
    #pragma unroll
    for (int i = 0; i < 7; ++i) {
        const int yy = y + i - 3;
        const float ymsk = ((yy >= 0) & (yy < HH)) ? 1.f : 0.f;
        const float* frow = fb + min(max(yy, 0), HH - 1) * WW;
        float fp[7];
        #pragma unroll
        for (int j = 0; j < 7; ++j)
            fp[j] = frow[xoff[j]] * (ymsk * xmsk[j]);   // branchless zero-pad
        float s7 = 0.f;
        #pragma unroll
        for (int j = 0; j < 7; ++j) s7 = fmaf(bv[9 + j], fp[j], s7);
        in7[i] = s7;
        if (i >= 1 && i <= 5) {
            float s5 = 0.f;
            #pragma unroll
            for (int j = 0; j < 5; ++j) s5 = fmaf(bv[4 + j], fp[1 + j], s5);
            in5[i - 1] = s5;
        }
        if (i >= 2 && i <= 4) {
            float s3 = 0.f;
            #pragma unroll
            for (int j = 0; j < 3; ++j) s3 = fmaf(bv[1 + j], fp[2 + j], s3);
            in3[i - 2] = s3;
        }
        if (i == 3) f1 = bv[0] * fp[3];
    }

    // keep a[]/kw loads from being hoisted above (they'd raise peak pressure)
    __builtin_amdgcn_sched_barrier(0);

    // phase 3: row weights + kernel_weight, final dots
    float a[16];
    #pragma unroll
    for (int q = 0; q < 16; ++q)
        a[q] = cp[(size_t)(q * 12) * HW];

    const float* kwp = kw + ((size_t)(b * NB + n) * 12 + t) * HW + pix;
    const float kw0 = kwp[0];
    const float kw1 = kwp[(size_t)3 * HW];
    const float kw2 = kwp[(size_t)6 * HW];
    const float kw3 = kwp[(size_t)9 * HW];

    float r7 = 0.f, r5 = 0.f, r3 = 0.f;
    #pragma unroll
    for (int i = 0; i < 7; ++i) r7 = fmaf(a[9 + i], in7[i], r7);
    #pragma unroll
    for (int i = 0; i < 5; ++i) r5 = fmaf(a[4 + i], in5[i], r5);
    #pragma unroll
    for (int i = 0; i < 3; ++i) r3 = fmaf(a[1 + i], in3[i], r3);
    const float r1 = a[0] * f1;

    part[tid] = fmaf(kw0, r7, fmaf(kw1, r5, fmaf(kw2, r3, kw3 * r1)));
}

// pred_img_i[b,n,t,pix] = 0.25 * sum_c part[b,n,c,t,pix]
// pred_img[b,t,pix]     = mean_n pred_img_i[b,n,t,pix]
__global__ __launch_bounds__(256) void finish(
    const float* __restrict__ part, float* __restrict__ out, float* __restrict__ pm)
{
    const int tid = blockIdx.x * blockDim.x + threadIdx.x;  // 27648
    if (tid >= 4 * TB * HW) return;
    const int pix = tid % HW;
    const int t = (tid / HW) % TB;
    const int b = tid / (HW * TB);

    float m = 0.f;
    #pragma unroll
    for (int n = 0; n < NB; ++n) {
        const float* p = part + ((size_t)((b * NB + n) * CB) * TB + t) * HW + pix;
        float s = p[0] + p[(size_t)TB * HW] + p[(size_t)2 * TB * HW] + p[(size_t)3 * TB * HW];
        s *= 0.25f;
        out[((size_t)(b * NB + n) * TB + t) * HW + pix] = s;
        m += s;
    }
    pm[((size_t)b * TB + t) * HW + pix] = m * 0.125f;
}

// ---- fallback monolithic kernel (used only if ws too small) ----
__global__ __launch_bounds__(256) void kconv_kernel(
    const float* __restrict__ frames, const float* __restrict__ core,
    const float* __restrict__ kw, float* __restrict__ out)
{
    const int tid = blockIdx.x * blockDim.x + threadIdx.x;
    const int x = tid % WW;
    const int y = (tid / WW) % HH;
    const int n = (tid / HW) % NB;
    const int b = tid / (HW * NB);
    const int pix = y * WW + x;

    float kwv[4][3];
    {
        const float* kwp = kw + (size_t)((b * NB + n) * 12) * HW + pix;
        #pragma unroll
        for (int s = 0; s < 4; ++s)
            #pragma unroll
            for (int t = 0; t < TB; ++t)
                kwv[s][t] = kwp[(size_t)(s * 3 + t) * HW];
    }
    float acc[TB] = {0.f, 0.f, 0.f};
    const float* fbase = frames + (size_t)((b * NB + n) * CB) * HW;
    const float* cbase = core + (size_t)b * 3072 * HW + pix;
    for (int c = 0; c < CB; ++c) {
        float fpv[49];
        #pragma unroll
        for (int i = 0; i < 7; ++i) {
            const int yy = y + i - 3;
            #pragma unroll
            for (int j = 0; j < 7; ++j) {
                const int xx = x + j - 3;
                const bool ok = (yy >= 0) & (yy < HH) & (xx >= 0) & (xx < WW);
                fpv[i * 7 + j] = ok ? fbase[(size_t)c * HW + yy * WW + xx] : 0.f;
            }
        }
        #pragma unroll
        for (int t = 0; t < TB; ++t) {
            float a[16], bv[16];
            const float* cp = cbase + (size_t)(((n * 32) * CB + c) * 3 + t) * HW;
            #pragma unroll
            for (int q = 0; q < 16; ++q) {
                a[q]  = cp[(size_t)(q * 12) * HW];
                bv[q] = cp[(size_t)((q + 16) * 12) * HW];
            }
            float tot = 0.f;
            {
                float r = 0.f;
                #pragma unroll
                for (int i = 0; i < 7; ++i) {
                    float inner = 0.f;
                    #pragma unroll
                    for (int j = 0; j < 7; ++j) inner = fmaf(bv[9 + j], fpv[i * 7 + j], inner);
                    r = fmaf(a[9 + i], inner, r);
                }
                tot = fmaf(kwv[0][t], r, tot);
            }
            {
                float r = 0.f;
                #pragma unroll
                for (int i = 0; i < 5; ++i) {
                    float inner = 0.f;
                    #pragma unroll
                    for (int j = 0; j < 5; ++j) inner = fmaf(bv[4 + j], fpv[(1 + i) * 7 + 1 + j], inner);
                    r = fmaf(a[4 + i], inner, r);
                }
                tot = fmaf(kwv[1][t], r, tot);
            }
            {
                float r = 0.f;
                #pragma unroll
                for (int i = 0; i < 3; ++i) {
                    float inner = 0.f;
                    #pragma unroll
                    for (int j = 0; j < 3; ++j) inner = fmaf(bv[1 + j], fpv[(2 + i) * 7 + 2 + j], inner);
                    r = fmaf(a[1 + i], inner, r);
                }
                tot = fmaf(kwv[2][t], r, tot);
            }
            tot = fmaf(kwv[3][t], a[0] * bv[0] * fpv[3 * 7 + 3], tot);
            acc[t] += 0.25f * tot;
        }
    }
    float* op = out + (size_t)((b * NB + n) * TB) * HW + pix;
    op[0] = acc[0]; op[HW] = acc[1]; op[2 * HW] = acc[2];
}

__global__ __launch_bounds__(256) void mean_fb(
    const float* __restrict__ pii, float* __restrict__ pm)
{
    const int tid = blockIdx.x * blockDim.x + threadIdx.x;  // 27648
    if (tid >= 4 * TB * HW) return;
    const int pix3 = tid % (TB * HW);
    const int b = tid / (TB * HW);
    float s = 0.f;
    #pragma unroll
    for (int n = 0; n < NB; ++n)
        s += pii[(size_t)((b * NB + n) * TB) * HW + pix3];
    pm[tid] = s * 0.125f;
}

extern "C" void kernel_launch(void* const* d_in, const int* in_sizes, int n_in,
                              void* d_out, int out_size, void* d_ws, size_t ws_size,
                              hipStream_t stream) {
    const float* frames = (const float*)d_in[0];
    const float* core   = (const float*)d_in[1];
    const float* kw     = (const float*)d_in[2];
    float* out = (float*)d_out;                 // pred_img_i: 221184 floats
    float* pm  = out + 4 * NB * TB * HW;        // pred_img:   27648 floats

    const size_t part_elems = (size_t)4 * NB * CB * TB * HW;  // 884736
    if (ws_size >= part_elems * sizeof(float)) {
        float* part = (float*)d_ws;
        kconv_part<<<(int)(part_elems / 256), 256, 0, stream>>>(frames, core, kw, part);
        finish<<<(4 * TB * HW + 255) / 256, 256, 0, stream>>>(part, out, pm);
    } else {
        kconv_kernel<<<(4 * NB * HW) / 256, 256, 0, stream>>>(frames, core, kw, out);
        mean_fb<<<(4 * TB * HW + 255) / 256, 256, 0, stream>>>(out, pm);
    }
}

// Round 7
// 27.259 us; speedup vs baseline: 2.5111x; 1.0558x over previous
//
#include <hip/hip_runtime.h>

#define HH 48
#define WW 48
#define HW 2304   // 48*48
#define NB 8      // N
#define CB 4      // COLOR
#define TB 3      // RGB

// pred_img_i[b,n,t,y,x] = 0.25 * sum_c sum_s kw[b,n,s,t,y,x] *
//     sum_{i,j in KxK} c1[b,n,cur_s+i,c,t,y,x]*c2[b,n,cur_s+j,c,t,y,x]
//                      * F[b,n,c, y+i+p_s-3, x+j+p_s-3]
// s=0:K=7,cur=9  s=1:K=5,cur=4  s=2:K=3,cur=1  s=3:K=1,cur=0
//
// Fused: block = 256 threads = 4 waves; wave c handles color c of the same
// 64-pixel chunk of one (b,n,t). Per-thread body = R6's phased structure
// (bv[16] -> row loop inner sums -> a[16]+kw -> partial). LDS c-reduce,
// wave 0 writes pred_img_i. No workspace round-trip, no finish kernel.
__global__ __launch_bounds__(256) void kconv_fused(
    const float* __restrict__ frames,   // (4, 8, 4, 48, 48)
    const float* __restrict__ core,     // (4, 3072, 48, 48)  ch=((n*32+q)*4+c)*3+t
    const float* __restrict__ kw,       // (4, 8, 4, 3, 48, 48)
    float* __restrict__ out)            // pred_img_i (4, 8, 3, 48, 48)
{
    const int blk = blockIdx.x;          // 4*8*3*36 = 3456
    const int pc  = blk % (HW / 64);     // 64-pixel chunk, 36 per image
    int rem = blk / (HW / 64);
    const int t = rem % TB; rem /= TB;
    const int n = rem % NB;
    const int b = rem / NB;
    const int tix = threadIdx.x;         // 0..255
    const int c   = tix >> 6;            // wave id = color
    const int p64 = tix & 63;
    const int pix = pc * 64 + p64;
    const int x = pix % WW;
    const int y = pix / WW;

    const float* cp = core + ((size_t)b * 3072 + (size_t)((n * 32) * CB + c) * 3 + t) * HW + pix;

    // phase 1: column weights bv[16]
    float bv[16];
    #pragma unroll
    for (int q = 0; q < 16; ++q)
        bv[q] = cp[(size_t)((q + 16) * 12) * HW];

    // x clamps/masks hoisted out of the row loop
    int   xoff[7];
    float xmsk[7];
    #pragma unroll
    for (int j = 0; j < 7; ++j) {
        const int xx = x + j - 3;
        xoff[j] = min(max(xx, 0), WW - 1);
        xmsk[j] = ((xx >= 0) & (xx < WW)) ? 1.f : 0.f;
    }

    const float* fb = frames + ((size_t)(b * NB + n) * CB + c) * HW;

    // phase 2: per-row inner sums (fp[] transient)
    float in7[7], in5[5], in3[3], f1 = 0.f;
    #pragma unroll
    for (int i = 0; i < 7; ++i) {
        const int yy = y + i - 3;
        const float ymsk = ((yy >= 0) & (yy < HH)) ? 1.f : 0.f;
        const float* frow = fb + min(max(yy, 0), HH - 1) * WW;
        float fp[7];
        #pragma unroll
        for (int j = 0; j < 7; ++j)
            fp[j] = frow[xoff[j]] * (ymsk * xmsk[j]);   // branchless zero-pad
        float s7 = 0.f;
        #pragma unroll
        for (int j = 0; j < 7; ++j) s7 = fmaf(bv[9 + j], fp[j], s7);
        in7[i] = s7;
        if (i >= 1 && i <= 5) {
            float s5 = 0.f;
            #pragma unroll
            for (int j = 0; j < 5; ++j) s5 = fmaf(bv[4 + j], fp[1 + j], s5);
            in5[i - 1] = s5;
        }
        if (i >= 2 && i <= 4) {
            float s3 = 0.f;
            #pragma unroll
            for (int j = 0; j < 3; ++j) s3 = fmaf(bv[1 + j], fp[2 + j], s3);
            in3[i - 2] = s3;
        }
        if (i == 3) f1 = bv[0] * fp[3];
    }

    // keep a[]/kw loads from being hoisted above (peak-pressure control)
    __builtin_amdgcn_sched_barrier(0);

    // phase 3: row weights + kernel_weight, final dots
    float a[16];
    #pragma unroll
    for (int q = 0; q < 16; ++q)
        a[q] = cp[(size_t)(q * 12) * HW];

    const float* kwp = kw + ((size_t)(b * NB + n) * 12 + t) * HW + pix;
    const float kw0 = kwp[0];
    const float kw1 = kwp[(size_t)3 * HW];
    const float kw2 = kwp[(size_t)6 * HW];
    const float kw3 = kwp[(size_t)9 * HW];

    float r7 = 0.f, r5 = 0.f, r3 = 0.f;
    #pragma unroll
    for (int i = 0; i < 7; ++i) r7 = fmaf(a[9 + i], in7[i], r7);
    #pragma unroll
    for (int i = 0; i < 5; ++i) r5 = fmaf(a[4 + i], in5[i], r5);
    #pragma unroll
    for (int i = 0; i < 3; ++i) r3 = fmaf(a[1 + i], in3[i], r3);
    const float r1 = a[0] * f1;

    const float val = fmaf(kw0, r7, fmaf(kw1, r5, fmaf(kw2, r3, kw3 * r1)));

    // LDS reduce over c (1 KB; 2 lanes/bank on write = free)
    __shared__ float lds[CB][64];
    lds[c][p64] = val;
    __syncthreads();
    if (tix < 64) {
        const float s = lds[0][tix] + lds[1][tix] + lds[2][tix] + lds[3][tix];
        out[((size_t)(b * NB + n) * TB + t) * HW + pc * 64 + tix] = 0.25f * s;
    }
}

// pred_img[b,t,pix] = mean_n pred_img_i[b,n,t,pix]
__global__ __launch_bounds__(256) void mean_fb(
    const float* __restrict__ pii, float* __restrict__ pm)
{
    const int tid = blockIdx.x * blockDim.x + threadIdx.x;  // 27648
    if (tid >= 4 * TB * HW) return;
    const int pix3 = tid % (TB * HW);
    const int b = tid / (TB * HW);
    float s = 0.f;
    #pragma unroll
    for (int n = 0; n < NB; ++n)
        s += pii[(size_t)((b * NB + n) * TB) * HW + pix3];
    pm[tid] = s * 0.125f;
}

extern "C" void kernel_launch(void* const* d_in, const int* in_sizes, int n_in,
                              void* d_out, int out_size, void* d_ws, size_t ws_size,
                              hipStream_t stream) {
    const float* frames = (const float*)d_in[0];
    const float* core   = (const float*)d_in[1];
    const float* kw     = (const float*)d_in[2];
    float* out = (float*)d_out;                 // pred_img_i: 221184 floats
    float* pm  = out + 4 * NB * TB * HW;        // pred_img:   27648 floats

    kconv_fused<<<4 * NB * TB * (HW / 64), 256, 0, stream>>>(frames, core, kw, out);
    mean_fb<<<(4 * TB * HW + 255) / 256, 256, 0, stream>>>(out, pm);
}